// Round 16
// baseline (823.064 us; speedup 1.0000x reference)
//
#include <hip/hip_runtime.h>
#include <hip/hip_bf16.h>

// GATConv — R16 DIAGNOSTIC ABLATION round.
// R13/R14/R15 all measured k2 ~4-5x above the static model (invariant across
// occupancy 2->4 waves/SIMD and pipeline depth). Per learn_hip m164/m165:
// template<MODE> ablation, within-probe. FULL variant (== R15 k2) runs last
// and writes out (correctness). Ablated variants write scratch with work
// multipliers REP so they exceed the ~150us harness-fill threshold and show
// up in the top-5 rocprof table:
//   k2<3,8>: LOADS_ONLY x8  -> load/latency path cost = dur/8
//   k2<1,2>: NO_MFMA   x2  -> P-compute(VALU+exp+cvt)+loads = dur/2
//   k2<2,2>: NO_EXP    x2  -> FULL minus v_exp             = dur/2
//   k2<0,1>: FULL      x1  -> writes d_out (unchanged R15 design)

typedef __bf16 bf16_t;
typedef bf16_t bf16x8 __attribute__((ext_vector_type(8)));
typedef float  f32x4  __attribute__((ext_vector_type(4)));
typedef int    i32x4  __attribute__((ext_vector_type(4)));

#define NN 8192
#define DD 128

// ---- kF: fused k1 (blocks 0..255) + kA pack (blocks 256..4351) ----
__global__ __launch_bounds__(512) void kF_pre(const float* __restrict__ X,
                                              const float* __restrict__ W,
                                              const float* __restrict__ a_src,
                                              const float* __restrict__ a_dst,
                                              const int* __restrict__ A,
                                              unsigned* __restrict__ bits,
                                              float* __restrict__ es,
                                              float* __restrict__ edv,
                                              bf16_t* __restrict__ VB) {
  __shared__ float Wl[DD * DD];
  __shared__ bf16_t Tl[DD][40];
  const int t = threadIdx.x;

  if (blockIdx.x >= 256) {
    const int w = (blockIdx.x - 256) * 512 + t;
    const i32x4* p = (const i32x4*)(A + (size_t)w * 32);
    i32x4 v[8];
    #pragma unroll
    for (int q = 0; q < 8; ++q) v[q] = p[q];
    unsigned m = 0;
    #pragma unroll
    for (int q = 0; q < 8; ++q) {
      #pragma unroll
      for (int e = 0; e < 4; ++e) m |= ((unsigned)v[q][e]) << (q * 4 + e);
    }
    const int row = w >> 8;
    const int c0 = (w & 255) << 5;
    if (row >= c0 && row < c0 + 32) m |= 1u << (row - c0);
    bits[w] = m;
    return;
  }

  const int rb = blockIdx.x << 5;

  if (t < 256) {
    const int k = t & 127;
    const float* av = (t < 128) ? a_src : a_dst;
    const f32x4* wrow = (const f32x4*)(W + k * DD);
    float s = 0.f;
    #pragma unroll
    for (int c4 = 0; c4 < 32; ++c4) {
      const f32x4 wv = wrow[c4];
      const f32x4 avv = *(const f32x4*)(av + c4 * 4);
      s += wv[0] * avv[0] + wv[1] * avv[1] + wv[2] * avv[2] + wv[3] * avv[3];
    }
    Wl[t] = s;
  }
  if (t < 64) Wl[256 + t] = 0.f;
  __syncthreads();

  {
    const int r = t >> 4, part = t & 15;
    const f32x4* xrow = (const f32x4*)(X + (size_t)(rb + r) * DD + part * 8);
    float s = 0.f, d = 0.f;
    #pragma unroll
    for (int q = 0; q < 2; ++q) {
      const f32x4 xv = xrow[q];
      const f32x4 sv = *(const f32x4*)(Wl + part * 8 + q * 4);
      const f32x4 dv = *(const f32x4*)(Wl + 128 + part * 8 + q * 4);
      s += xv[0] * sv[0] + xv[1] * sv[1] + xv[2] * sv[2] + xv[3] * sv[3];
      d += xv[0] * dv[0] + xv[1] * dv[1] + xv[2] * dv[2] + xv[3] * dv[3];
    }
    atomicAdd(&Wl[256 + r], s);
    atomicAdd(&Wl[288 + r], d);
  }
  __syncthreads();
  if (t < 32) {
    es[rb + t] = Wl[256 + t];
  } else if (t < 64) {
    edv[rb + t - 32] = Wl[288 + t - 32];
  }
  __syncthreads();

  for (int idx = t; idx < DD * DD; idx += 512) Wl[idx] = W[idx];
  __syncthreads();

  const int c = t & 127;
  const int r0 = t >> 7;
  for (int rr = 0; rr < 8; ++rr) {
    const int r = (rr << 2) + r0;
    const f32x4* xrow = (const f32x4*)(X + (size_t)(rb + r) * DD);
    float acc = 0.f;
    #pragma unroll
    for (int k4 = 0; k4 < 32; ++k4) {
      const f32x4 xv = xrow[k4];
      acc += xv[0] * Wl[(k4 * 4 + 0) * DD + c] + xv[1] * Wl[(k4 * 4 + 1) * DD + c] +
             xv[2] * Wl[(k4 * 4 + 2) * DD + c] + xv[3] * Wl[(k4 * 4 + 3) * DD + c];
    }
    Tl[c][r] = (bf16_t)acc;
  }
  __syncthreads();

  {
    const int cb = t >> 6;
    const int lane = t & 63;
    const int col = (cb << 4) + (lane & 15);
    const int rloc = (lane >> 4) << 3;
    const bf16x8 u = *(const bf16x8*)&Tl[col][rloc];
    *(bf16x8*)(VB + ((((size_t)(rb >> 5) << 3) + cb) * 64 + lane) * 8) = u;
  }
}

// ---- K2 (templated ablation). MODE: 0=FULL 1=NO_MFMA 2=NO_EXP 3=LOADS_ONLY ----
template <int MODE, int REP>
__global__ __launch_bounds__(512, 4) void k2_gat(const unsigned* __restrict__ bits,
                                                 const float* __restrict__ es,
                                                 const float* __restrict__ edv,
                                                 const bf16_t* __restrict__ VB,
                                                 float* __restrict__ out) {
  __shared__ float numL[32 * 64];
  __shared__ float denL[32];
  const int t = threadIdx.x;
  const int lane = t & 63, ws = t >> 6;
  const int l16 = lane & 15, lk = lane >> 4;
  const int rt = blockIdx.x >> 1;
  const int ch = blockIdx.x & 1;
  const int rb = rt << 5;

  for (int idx = t; idx < 32 * 64; idx += 512) numL[idx] = 0.f;
  if (t < 32) denL[t] = 0.f;

  const int r0 = rb + l16;
  const int r1 = r0 + 16;
  const float es0 = es[r0];
  const float es1 = es[r1];

  const unsigned* pB0 = bits + (size_t)r0 * 256 + (ws << 5);
  const unsigned* pB1 = bits + (size_t)r1 * 256 + (ws << 5);
  const float* ped = edv + (ws << 10) + (lk << 3);
  const bf16_t* pV = VB + (((size_t)(ws << 5) * 8 + (ch << 2)) * 64 + lane) * 8;

  f32x4 acc0[4], acc1[4];
  #pragma unroll
  for (int cf = 0; cf < 4; ++cf) {
    acc0[cf] = f32x4{0.f, 0.f, 0.f, 0.f};
    acc1[cf] = f32x4{0.f, 0.f, 0.f, 0.f};
  }
  float dsum0 = 0.f, dsum1 = 0.f;

  unsigned bA0, bA1, bB0, bB1;
  f32x4 eA0, eA1, eB0, eB1;
  bf16x8 vA0, vA1, vA2, vA3, vB0, vB1, vB2, vB3;

  for (int rep = 0; rep < REP; ++rep) {
    // prologue: load phase A for s=0
    bA0 = pB0[0];
    bA1 = pB1[0];
    eA0 = *(const f32x4*)ped;
    eA1 = *(const f32x4*)(ped + 4);
    vA0 = *(const bf16x8*)(pV);
    vA1 = *(const bf16x8*)(pV + 512);
    vA2 = *(const bf16x8*)(pV + 1024);
    vA3 = *(const bf16x8*)(pV + 1536);

    auto step = [&](int s, unsigned& cb0, unsigned& cb1, f32x4& ce0, f32x4& ce1,
                    bf16x8& cv0, bf16x8& cv1, bf16x8& cv2, bf16x8& cv3, unsigned& nb0,
                    unsigned& nb1, f32x4& ne0, f32x4& ne1, bf16x8& nv0, bf16x8& nv1,
                    bf16x8& nv2, bf16x8& nv3) {
      // (1) issue step s+1's loads
      if (s + 1 < 32) {
        nb0 = pB0[s + 1];
        nb1 = pB1[s + 1];
        const int o = (s + 1) << 5;
        ne0 = *(const f32x4*)(ped + o);
        ne1 = *(const f32x4*)(ped + o + 4);
        const bf16_t* pv = pV + (size_t)(s + 1) * 4096;
        nv0 = *(const bf16x8*)(pv);
        nv1 = *(const bf16x8*)(pv + 512);
        nv2 = *(const bf16x8*)(pv + 1024);
        nv3 = *(const bf16x8*)(pv + 1536);
      }
      if constexpr (MODE == 3) {
        // LOADS_ONLY: keep everything alive, no compute
        asm volatile("" ::"v"(cv0), "v"(cv1), "v"(cv2), "v"(cv3));
        asm volatile("" ::"v"(ce0), "v"(ce1), "v"(cb0), "v"(cb1));
        return;
      }
      // (2) P in-reg
      const unsigned m0 = cb0 >> (lk << 3);
      const unsigned m1 = cb1 >> (lk << 3);
      bf16x8 pa0, pa1;
      float p0s = 0.f, p1s = 0.f;
      #pragma unroll
      for (int e = 0; e < 8; ++e) {
        const float edq = (e < 4) ? ce0[e] : ce1[e - 4];
        float x0 = es0 + edq;
        x0 = fmaxf(x0, 0.2f * x0);
        float x1 = es1 + edq;
        x1 = fmaxf(x1, 0.2f * x1);
        float p0, p1;
        if constexpr (MODE == 2) {  // NO_EXP: masked leaky value directly
          p0 = ((m0 >> e) & 1u) ? x0 : 0.f;
          p1 = ((m1 >> e) & 1u) ? x1 : 0.f;
        } else {
          p0 = ((m0 >> e) & 1u) ? __expf(x0) : 0.f;
          p1 = ((m1 >> e) & 1u) ? __expf(x1) : 0.f;
        }
        p0s += p0;
        p1s += p1;
        pa0[e] = (bf16_t)p0;
        pa1[e] = (bf16_t)p1;
      }
      dsum0 += p0s;
      dsum1 += p1s;
      if constexpr (MODE == 1) {
        // NO_MFMA: keep pa + vb alive
        asm volatile("" ::"v"(pa0), "v"(pa1));
        asm volatile("" ::"v"(cv0), "v"(cv1), "v"(cv2), "v"(cv3));
        return;
      }
      // (3) 8 MFMA
      acc0[0] = __builtin_amdgcn_mfma_f32_16x16x32_bf16(pa0, cv0, acc0[0], 0, 0, 0);
      acc1[0] = __builtin_amdgcn_mfma_f32_16x16x32_bf16(pa1, cv0, acc1[0], 0, 0, 0);
      acc0[1] = __builtin_amdgcn_mfma_f32_16x16x32_bf16(pa0, cv1, acc0[1], 0, 0, 0);
      acc1[1] = __builtin_amdgcn_mfma_f32_16x16x32_bf16(pa1, cv1, acc1[1], 0, 0, 0);
      acc0[2] = __builtin_amdgcn_mfma_f32_16x16x32_bf16(pa0, cv2, acc0[2], 0, 0, 0);
      acc1[2] = __builtin_amdgcn_mfma_f32_16x16x32_bf16(pa1, cv2, acc1[2], 0, 0, 0);
      acc0[3] = __builtin_amdgcn_mfma_f32_16x16x32_bf16(pa0, cv3, acc0[3], 0, 0, 0);
      acc1[3] = __builtin_amdgcn_mfma_f32_16x16x32_bf16(pa1, cv3, acc1[3], 0, 0, 0);
    };

    #pragma unroll 1
    for (int g = 0; g < 16; ++g) {
      step(2 * g, bA0, bA1, eA0, eA1, vA0, vA1, vA2, vA3,
           bB0, bB1, eB0, eB1, vB0, vB1, vB2, vB3);
      step(2 * g + 1, bB0, bB1, eB0, eB1, vB0, vB1, vB2, vB3,
           bA0, bA1, eA0, eA1, vA0, vA1, vA2, vA3);
    }
  }

  // ---- epilogue (all modes; ablated modes target scratch) ----
  dsum0 += __shfl_xor(dsum0, 16, 64);
  dsum0 += __shfl_xor(dsum0, 32, 64);
  dsum1 += __shfl_xor(dsum1, 16, 64);
  dsum1 += __shfl_xor(dsum1, 32, 64);
  __syncthreads();
  if (lane < 16) {
    atomicAdd(&denL[l16], dsum0);
    atomicAdd(&denL[16 + l16], dsum1);
  }
  #pragma unroll
  for (int cf = 0; cf < 4; ++cf) {
    #pragma unroll
    for (int r = 0; r < 4; ++r) {
      atomicAdd(&numL[((lk << 2) + r) * 64 + (cf << 4) + l16], acc0[cf][r]);
      atomicAdd(&numL[(16 + (lk << 2) + r) * 64 + (cf << 4) + l16], acc1[cf][r]);
    }
  }
  __syncthreads();

  {
    const int row = t >> 4;
    const int c0 = (t & 15) << 2;
    const float rd = 1.f / denL[row];
    f32x4 o;
    #pragma unroll
    for (int q = 0; q < 4; ++q) {
      float v = numL[row * 64 + c0 + q] * rd;
      o[q] = v > 0.f ? v : (__expf(v) - 1.f);
    }
    *(f32x4*)(out + (size_t)(rb + row) * DD + (ch << 6) + c0) = o;
  }
}

extern "C" void kernel_launch(void* const* d_in, const int* in_sizes, int n_in,
                              void* d_out, int out_size, void* d_ws, size_t ws_size,
                              hipStream_t stream) {
  const float* X = (const float*)d_in[0];
  const int* A = (const int*)d_in[1];
  const float* W = (const float*)d_in[2];
  const float* a_src = (const float*)d_in[3];
  const float* a_dst = (const float*)d_in[4];
  float* out = (float*)d_out;

  char* w = (char*)d_ws;
  unsigned* bitsv = (unsigned*)(w + 0);   // 8 MB
  bf16_t* VB = (bf16_t*)(w + 8388608);    // 2 MB
  float* es = (float*)(w + 10485760);     // 32 KB
  float* edv = (float*)(w + 10518528);    // 32 KB
  float* scratch = (float*)(w + 10551296);  // 4 MB ablation sink

  hipLaunchKernelGGL(kF_pre, dim3(256 + 4096), dim3(512), 0, stream, X, W, a_src,
                     a_dst, A, bitsv, es, edv, VB);
  hipLaunchKernelGGL(HIP_KERNEL_NAME(k2_gat<3, 8>), dim3(512), dim3(512), 0, stream,
                     bitsv, es, edv, VB, scratch);
  hipLaunchKernelGGL(HIP_KERNEL_NAME(k2_gat<1, 2>), dim3(512), dim3(512), 0, stream,
                     bitsv, es, edv, VB, scratch);
  hipLaunchKernelGGL(HIP_KERNEL_NAME(k2_gat<2, 2>), dim3(512), dim3(512), 0, stream,
                     bitsv, es, edv, VB, scratch);
  hipLaunchKernelGGL(HIP_KERNEL_NAME(k2_gat<0, 1>), dim3(512), dim3(512), 0, stream,
                     bitsv, es, edv, VB, out);
}

// Round 17
// 226.751 us; speedup vs baseline: 3.6298x; 3.6298x over previous
//
#include <hip/hip_runtime.h>
#include <hip/hip_bf16.h>

// GATConv, N=8192, F_in=F_out=128, dense 0/1 adjacency (int32).
// Rank-1 logits: e_ij = LeakyReLU(es_i + ed_j). exp safe in f32 -> additive
// softmax partials.
//
// R17 (driven by R16 ablation: LOADS_ONLY alone = 52.7us -> k2 is vector-mem
// path bound; register-direct VB costs 512MB L2 regardless of j-split):
//  k2: BM=128 LDS-staged GEMM. 64 rowtiles x 8 jo = 512 blocks (2/CU).
//      Per 64-j step: 16KB VB chunk via global_load_lds (frag-major VB ->
//      LINEAR LDS dest, conflict-free ds_read), shared by 8 waves (4rg x 2ch)
//      -> VB L2 traffic 128MB (4x cut), L1 request path 4x cut. Counted
//      vmcnt(2) + raw s_barrier keeps glds in flight a full step. bits/ed
//      1-step-ahead phase regs. Epilogue: LDS 64KB merge -> full-line
//      coalesced num stores (no write amplification). k3 sums 8 slices.

typedef __bf16 bf16_t;
typedef bf16_t bf16x8 __attribute__((ext_vector_type(8)));
typedef float  f32x4  __attribute__((ext_vector_type(4)));
typedef int    i32x4  __attribute__((ext_vector_type(4)));

#define NN 8192
#define DD 128
#define NSLICE 8

#define GLOAD_LDS16(src, dst)                                                  \
  __builtin_amdgcn_global_load_lds(                                            \
      (const __attribute__((address_space(1))) unsigned int*)(src),            \
      (__attribute__((address_space(3))) unsigned int*)(dst), 16, 0, 0)

// ---- kF: fused k1 (blocks 0..255) + kA pack (blocks 256..4351) ----
__global__ __launch_bounds__(512) void kF_pre(const float* __restrict__ X,
                                              const float* __restrict__ W,
                                              const float* __restrict__ a_src,
                                              const float* __restrict__ a_dst,
                                              const int* __restrict__ A,
                                              unsigned* __restrict__ bits,
                                              float* __restrict__ es,
                                              float* __restrict__ edv,
                                              bf16_t* __restrict__ VB) {
  __shared__ float Wl[DD * DD];
  __shared__ bf16_t Tl[DD][40];
  const int t = threadIdx.x;

  if (blockIdx.x >= 256) {
    const int w = (blockIdx.x - 256) * 512 + t;
    const i32x4* p = (const i32x4*)(A + (size_t)w * 32);
    i32x4 v[8];
    #pragma unroll
    for (int q = 0; q < 8; ++q) v[q] = p[q];
    unsigned m = 0;
    #pragma unroll
    for (int q = 0; q < 8; ++q) {
      #pragma unroll
      for (int e = 0; e < 4; ++e) m |= ((unsigned)v[q][e]) << (q * 4 + e);
    }
    const int row = w >> 8;
    const int c0 = (w & 255) << 5;
    if (row >= c0 && row < c0 + 32) m |= 1u << (row - c0);
    bits[w] = m;
    return;
  }

  const int rb = blockIdx.x << 5;

  if (t < 256) {
    const int k = t & 127;
    const float* av = (t < 128) ? a_src : a_dst;
    const f32x4* wrow = (const f32x4*)(W + k * DD);
    float s = 0.f;
    #pragma unroll
    for (int c4 = 0; c4 < 32; ++c4) {
      const f32x4 wv = wrow[c4];
      const f32x4 avv = *(const f32x4*)(av + c4 * 4);
      s += wv[0] * avv[0] + wv[1] * avv[1] + wv[2] * avv[2] + wv[3] * avv[3];
    }
    Wl[t] = s;
  }
  if (t < 64) Wl[256 + t] = 0.f;
  __syncthreads();

  {
    const int r = t >> 4, part = t & 15;
    const f32x4* xrow = (const f32x4*)(X + (size_t)(rb + r) * DD + part * 8);
    float s = 0.f, d = 0.f;
    #pragma unroll
    for (int q = 0; q < 2; ++q) {
      const f32x4 xv = xrow[q];
      const f32x4 sv = *(const f32x4*)(Wl + part * 8 + q * 4);
      const f32x4 dv = *(const f32x4*)(Wl + 128 + part * 8 + q * 4);
      s += xv[0] * sv[0] + xv[1] * sv[1] + xv[2] * sv[2] + xv[3] * sv[3];
      d += xv[0] * dv[0] + xv[1] * dv[1] + xv[2] * dv[2] + xv[3] * dv[3];
    }
    atomicAdd(&Wl[256 + r], s);
    atomicAdd(&Wl[288 + r], d);
  }
  __syncthreads();
  if (t < 32) {
    es[rb + t] = Wl[256 + t];
  } else if (t < 64) {
    edv[rb + t - 32] = Wl[288 + t - 32];
  }
  __syncthreads();

  for (int idx = t; idx < DD * DD; idx += 512) Wl[idx] = W[idx];
  __syncthreads();

  const int c = t & 127;
  const int r0 = t >> 7;
  for (int rr = 0; rr < 8; ++rr) {
    const int r = (rr << 2) + r0;
    const f32x4* xrow = (const f32x4*)(X + (size_t)(rb + r) * DD);
    float acc = 0.f;
    #pragma unroll
    for (int k4 = 0; k4 < 32; ++k4) {
      const f32x4 xv = xrow[k4];
      acc += xv[0] * Wl[(k4 * 4 + 0) * DD + c] + xv[1] * Wl[(k4 * 4 + 1) * DD + c] +
             xv[2] * Wl[(k4 * 4 + 2) * DD + c] + xv[3] * Wl[(k4 * 4 + 3) * DD + c];
    }
    Tl[c][r] = (bf16_t)acc;
  }
  __syncthreads();

  // VB[((jb*8 + cb)*64 + lane)*8 + e] = H[jb*32 + (lane>>4)*8 + e][cb*16 + (lane&15)]
  {
    const int cb = t >> 6;
    const int lane = t & 63;
    const int col = (cb << 4) + (lane & 15);
    const int rloc = (lane >> 4) << 3;
    const bf16x8 u = *(const bf16x8*)&Tl[col][rloc];
    *(bf16x8*)(VB + ((((size_t)(rb >> 5) << 3) + cb) * 64 + lane) * 8) = u;
  }
}

// ---- K2: LDS-staged masked GEMM, BM=128. 512 blocks (2/CU) x 512 thr. ----
// Block = 128 rows x 1024-j slice (jo). 16 steps of 64 j. Waves (rg 0..3,
// ch 0..1): rows rb+rg*32+{0..31}, cols ch*64. Per step: stage 16KB VB ->
// LDS (glds, linear), P in-reg (32 exp), 8 ds_read + 16 MFMA.
__global__ __launch_bounds__(512, 4) void k2_gat(const unsigned* __restrict__ bits,
                                                 const float* __restrict__ es,
                                                 const float* __restrict__ edv,
                                                 const bf16_t* __restrict__ VB,
                                                 float* __restrict__ num,
                                                 float* __restrict__ denP) {
  __shared__ __align__(16) unsigned char LB[65536];  // [0,32K) V dbuf; all 64K = merge
  const int t = threadIdx.x;
  const int lane = t & 63, w = t >> 6;
  const int l16 = lane & 15, lk = lane >> 4;
  const int rg = w >> 1, ch = w & 1;
  const int rt = blockIdx.x >> 3;  // 0..63
  const int jo = blockIdx.x & 7;   // 0..7
  const int rb = rt << 7;

  const int rA = rb + (rg << 5) + l16;
  const int rB = rA + 16;
  const float esA = es[rA], esB = es[rB];

  const uint2* pBA = (const uint2*)(bits + (size_t)rA * 256 + (jo << 5));
  const uint2* pBB = (const uint2*)(bits + (size_t)rB * 256 + (jo << 5));
  const float* pe = edv + (jo << 10) + (lk << 3);

  // glds: wave stages unit-groups (2w, 2w+1); unit-group g covers (kc=g>>3, cb=g&7)
  const unsigned char* src0 = (const unsigned char*)VB + (size_t)jo * 262144 +
                              (unsigned)(w << 1) * 1024 + (unsigned)lane * 16;

  auto STAGE = [&](int s, int bufsel) {
    const unsigned char* sp = src0 + (unsigned)s * 16384;
    unsigned char* dp = LB + (bufsel << 14) + (w << 11);
    GLOAD_LDS16(sp, dp);
    GLOAD_LDS16(sp + 1024, dp + 1024);
  };

  f32x4 accA[4], accB[4];
  #pragma unroll
  for (int cf = 0; cf < 4; ++cf) {
    accA[cf] = f32x4{0.f, 0.f, 0.f, 0.f};
    accB[cf] = f32x4{0.f, 0.f, 0.f, 0.f};
  }
  float dA = 0.f, dB = 0.f;

  // prologue: stage step 0, load phase-0 bits/ed
  STAGE(0, 0);
  uint2 cAb = pBA[0], cBb = pBB[0];
  f32x4 c0 = *(const f32x4*)pe, c1 = *(const f32x4*)(pe + 4);
  f32x4 c2 = *(const f32x4*)(pe + 32), c3 = *(const f32x4*)(pe + 36);
  uint2 nAb, nBb;
  f32x4 n0, n1, n2, n3;

  auto step = [&](int s, uint2& xA, uint2& xB, f32x4& y0, f32x4& y1, f32x4& y2,
                  f32x4& y3, uint2& zA, uint2& zB, f32x4& q0, f32x4& q1, f32x4& q2,
                  f32x4& q3) {
    // (1) P for this step's 64 j (2 kc chunks of 32), from phase regs
    bf16x8 pA0, pA1, pB0, pB1;
    float sA = 0.f, sB = 0.f;
    {
      const unsigned mA = xA.x >> (lk << 3), mB = xB.x >> (lk << 3);
      #pragma unroll
      for (int e = 0; e < 8; ++e) {
        const float edq = (e < 4) ? y0[e] : y1[e - 4];
        float a = esA + edq;
        a = fmaxf(a, 0.2f * a);
        float b = esB + edq;
        b = fmaxf(b, 0.2f * b);
        const float pa = ((mA >> e) & 1u) ? __expf(a) : 0.f;
        const float pb = ((mB >> e) & 1u) ? __expf(b) : 0.f;
        sA += pa;
        sB += pb;
        pA0[e] = (bf16_t)pa;
        pB0[e] = (bf16_t)pb;
      }
    }
    {
      const unsigned mA = xA.y >> (lk << 3), mB = xB.y >> (lk << 3);
      #pragma unroll
      for (int e = 0; e < 8; ++e) {
        const float edq = (e < 4) ? y2[e] : y3[e - 4];
        float a = esA + edq;
        a = fmaxf(a, 0.2f * a);
        float b = esB + edq;
        b = fmaxf(b, 0.2f * b);
        const float pa = ((mA >> e) & 1u) ? __expf(a) : 0.f;
        const float pb = ((mB >> e) & 1u) ? __expf(b) : 0.f;
        sA += pa;
        sB += pb;
        pA1[e] = (bf16_t)pa;
        pB1[e] = (bf16_t)pb;
      }
    }
    dA += sA;
    dB += sB;
    // (2) next phase: bits/ed regs, then VB stage (glds LAST -> newest 2)
    __builtin_amdgcn_sched_barrier(0);
    if (s + 1 < 16) {
      zA = pBA[s + 1];
      zB = pBB[s + 1];
      const float* p = pe + ((s + 1) << 6);
      q0 = *(const f32x4*)p;
      q1 = *(const f32x4*)(p + 4);
      q2 = *(const f32x4*)(p + 32);
      q3 = *(const f32x4*)(p + 36);
      STAGE(s + 1, (s + 1) & 1);
      __builtin_amdgcn_sched_barrier(0);
      // keep ONLY the 2 glds in flight; drains glds(s) (and the small loads)
      asm volatile("s_waitcnt vmcnt(2)" ::: "memory");
    } else {
      __builtin_amdgcn_sched_barrier(0);
      asm volatile("s_waitcnt vmcnt(0)" ::: "memory");
    }
    __builtin_amdgcn_s_barrier();  // buf[s&1] ready for all waves
    // (3) ds_read + MFMA (conflict-free: lane*16 linear)
    const unsigned char* B =
        LB + ((s & 1) << 14) + (unsigned)(ch << 2) * 1024 + (unsigned)lane * 16;
    #pragma unroll
    for (int cf = 0; cf < 4; ++cf) {
      const bf16x8 v0 = *(const bf16x8*)(B + cf * 1024);
      accA[cf] = __builtin_amdgcn_mfma_f32_16x16x32_bf16(pA0, v0, accA[cf], 0, 0, 0);
      accB[cf] = __builtin_amdgcn_mfma_f32_16x16x32_bf16(pB0, v0, accB[cf], 0, 0, 0);
    }
    #pragma unroll
    for (int cf = 0; cf < 4; ++cf) {
      const bf16x8 v1 = *(const bf16x8*)(B + 8192 + cf * 1024);
      accA[cf] = __builtin_amdgcn_mfma_f32_16x16x32_bf16(pA1, v1, accA[cf], 0, 0, 0);
      accB[cf] = __builtin_amdgcn_mfma_f32_16x16x32_bf16(pB1, v1, accB[cf], 0, 0, 0);
    }
    __builtin_amdgcn_sched_barrier(0);
    __builtin_amdgcn_s_barrier();  // all reads of buf[s&1] done
  };

  #pragma unroll 1
  for (int g = 0; g < 8; ++g) {
    step(2 * g, cAb, cBb, c0, c1, c2, c3, nAb, nBb, n0, n1, n2, n3);
    step(2 * g + 1, nAb, nBb, n0, n1, n2, n3, cAb, cBb, c0, c1, c2, c3);
  }

  // ---- den: shfl-reduce over lk, plain stores (16 consecutive rows) ----
  dA += __shfl_xor(dA, 16, 64);
  dA += __shfl_xor(dA, 32, 64);
  dB += __shfl_xor(dB, 16, 64);
  dB += __shfl_xor(dB, 32, 64);
  if (ch == 0 && lane < 16) {
    denP[(size_t)jo * NN + rA] = dA;
    denP[(size_t)jo * NN + rB] = dB;
  }

  // ---- num: LDS merge (reuse LB as [128][128] f32) -> coalesced stores ----
  float* M = (float*)LB;
  #pragma unroll
  for (int cf = 0; cf < 4; ++cf) {
    const int col = (ch << 6) + (cf << 4) + l16;
    #pragma unroll
    for (int r = 0; r < 4; ++r) {
      // C/D: row = (lane>>4)*4 + reg, col = lane&15 (validated layout)
      M[((rg << 5) + (lk << 2) + r) * DD + col] = accA[cf][r];
      M[((rg << 5) + 16 + (lk << 2) + r) * DD + col] = accB[cf][r];
    }
  }
  __syncthreads();
  float* nq = num + (size_t)jo * ((size_t)NN * DD);
  const int orow = t >> 5;       // 0..15
  const int oc = (t & 31) << 2;  // 0..124
  #pragma unroll
  for (int p = 0; p < 8; ++p) {
    const int rl = orow + (p << 4);
    *(f32x4*)(nq + (size_t)(rb + rl) * DD + oc) = *(const f32x4*)&M[rl * DD + oc];
  }
}

// ---- K3: out = elu( (sum_s num_s) / (sum_s den_s) ) ----
__global__ __launch_bounds__(256) void k3_fin(const float* __restrict__ num,
                                              const float* __restrict__ denP,
                                              float* __restrict__ out) {
  const int g = blockIdx.x * 256 + threadIdx.x;
  const size_t b = (size_t)g * 8;
  const int row = (int)(b >> 7);
  float den = 0.f;
  #pragma unroll
  for (int q = 0; q < NSLICE; ++q) den += denP[(size_t)q * NN + row];
  const float rd = 1.f / den;
  f32x4 s0 = {0.f, 0.f, 0.f, 0.f}, s1 = {0.f, 0.f, 0.f, 0.f};
  #pragma unroll
  for (int q = 0; q < NSLICE; ++q) {
    const float* nb = num + (size_t)q * ((size_t)NN * DD);
    s0 += *(const f32x4*)(nb + b);
    s1 += *(const f32x4*)(nb + b + 4);
  }
  #pragma unroll
  for (int e = 0; e < 4; ++e) {
    float v = s0[e] * rd;
    s0[e] = v > 0.f ? v : (__expf(v) - 1.f);
    v = s1[e] * rd;
    s1[e] = v > 0.f ? v : (__expf(v) - 1.f);
  }
  *(f32x4*)(out + b) = s0;
  *(f32x4*)(out + b + 4) = s1;
}

extern "C" void kernel_launch(void* const* d_in, const int* in_sizes, int n_in,
                              void* d_out, int out_size, void* d_ws, size_t ws_size,
                              hipStream_t stream) {
  const float* X = (const float*)d_in[0];
  const int* A = (const int*)d_in[1];
  const float* W = (const float*)d_in[2];
  const float* a_src = (const float*)d_in[3];
  const float* a_dst = (const float*)d_in[4];
  float* out = (float*)d_out;

  char* w = (char*)d_ws;
  unsigned* bitsv = (unsigned*)(w + 0);  // 8 MB
  bf16_t* VB = (bf16_t*)(w + 8388608);   // 2 MB frag-major H
  float* es = (float*)(w + 10485760);    // 32 KB
  float* edv = (float*)(w + 10518528);   // 32 KB
  float* denP = (float*)(w + 10551296);  // 8 x 32 KB
  float* num = (float*)(w + 10813440);   // 8 x 4 MB (total ~42.3 MB)

  hipLaunchKernelGGL(kF_pre, dim3(256 + 4096), dim3(512), 0, stream, X, W, a_src,
                     a_dst, A, bitsv, es, edv, VB);
  hipLaunchKernelGGL(k2_gat, dim3(512), dim3(512), 0, stream, bitsv, es, edv, VB, num,
                     denP);
  hipLaunchKernelGGL(k3_fin, dim3(512), dim3(256), 0, stream, num, denP, out);
}